// Round 1
// baseline (8867.786 us; speedup 1.0000x reference)
//
#include <hip/hip_runtime.h>
#include <hip/hip_bf16.h>
#include <stdint.h>

// Problem constants (NamedEntityRecognitionModel)
#define VOCAB 50000
#define TAGS  32
#define EMB   256
#define HID   512
#define HSZ   256        // per-direction hidden
#define G4H   1024       // 4*HSZ
#define BATCH 64
#define TLEN  512
#define MTOK  (BATCH * TLEN)   // 32768

// ---------------------------------------------------------------------------
// helpers
// ---------------------------------------------------------------------------
__device__ __forceinline__ float bf_lo(unsigned u) { return __uint_as_float(u << 16); }
__device__ __forceinline__ float bf_hi(unsigned u) { return __uint_as_float(u & 0xffff0000u); }

__device__ __forceinline__ float sigmoid_f(float x) { return 1.0f / (1.0f + __expf(-x)); }
__device__ __forceinline__ float tanh_f(float x) {
    // tanh(x) = 1 - 2/(e^{2x}+1); robust at both extremes with __expf
    return 1.0f - 2.0f / (__expf(2.0f * x) + 1.0f);
}

// ---------------------------------------------------------------------------
// K1: cast Wh_f / Wh_b (each [1024,256] f32) to bf16
// ---------------------------------------------------------------------------
__global__ void cast_wh_kernel(const float* __restrict__ WhF, const float* __restrict__ WhB,
                               __hip_bfloat16* __restrict__ of, __hip_bfloat16* __restrict__ ob) {
    int i = blockIdx.x * 256 + threadIdx.x;   // grid = 1024 blocks -> 262144
    of[i] = __float2bfloat16(WhF[i]);
    ob[i] = __float2bfloat16(WhB[i]);
}

// ---------------------------------------------------------------------------
// K2: xW[m,g] = embed[X[m]] . Wi[g] + bias[g]   (fp32 tiled GEMM, gather fused)
// grid (M/64, 1024/64, 2), block 256
// ---------------------------------------------------------------------------
__global__ void gemm_xw_kernel(const int* __restrict__ X, const float* __restrict__ embed,
                               const float* __restrict__ WiF, const float* __restrict__ bF,
                               const float* __restrict__ WiB, const float* __restrict__ bB,
                               __hip_bfloat16* __restrict__ xWf, __hip_bfloat16* __restrict__ xWb) {
    __shared__ float As[64][17];
    __shared__ float Bs[64][17];
    const int tid = threadIdx.x;
    const int dir = blockIdx.z;
    const float* Wi   = dir ? WiB : WiF;
    const float* bias = dir ? bB  : bF;
    __hip_bfloat16* out = dir ? xWb : xWf;

    const int m0 = blockIdx.x * 64;
    const int g0 = blockIdx.y * 64;
    const int tx = tid & 15, ty = tid >> 4;

    const int lrow = tid >> 2;        // 0..63 (tile row this thread loads)
    const int lk   = (tid & 3) * 4;   // 0,4,8,12
    const int erow = X[m0 + lrow];    // embedding gather index

    float acc[4][4] = {};

    for (int k0 = 0; k0 < EMB; k0 += 16) {
        const float4 av = *(const float4*)&embed[(size_t)erow * EMB + k0 + lk];
        const float4 bv = *(const float4*)&Wi[(size_t)(g0 + lrow) * EMB + k0 + lk];
        __syncthreads();
        As[lrow][lk + 0] = av.x; As[lrow][lk + 1] = av.y;
        As[lrow][lk + 2] = av.z; As[lrow][lk + 3] = av.w;
        Bs[lrow][lk + 0] = bv.x; Bs[lrow][lk + 1] = bv.y;
        Bs[lrow][lk + 2] = bv.z; Bs[lrow][lk + 3] = bv.w;
        __syncthreads();
#pragma unroll
        for (int kk = 0; kk < 16; ++kk) {
            float a0 = As[ty * 4 + 0][kk], a1 = As[ty * 4 + 1][kk];
            float a2 = As[ty * 4 + 2][kk], a3 = As[ty * 4 + 3][kk];
            float b0 = Bs[tx * 4 + 0][kk], b1 = Bs[tx * 4 + 1][kk];
            float b2 = Bs[tx * 4 + 2][kk], b3 = Bs[tx * 4 + 3][kk];
            acc[0][0] += a0 * b0; acc[0][1] += a0 * b1; acc[0][2] += a0 * b2; acc[0][3] += a0 * b3;
            acc[1][0] += a1 * b0; acc[1][1] += a1 * b1; acc[1][2] += a1 * b2; acc[1][3] += a1 * b3;
            acc[2][0] += a2 * b0; acc[2][1] += a2 * b1; acc[2][2] += a2 * b2; acc[2][3] += a2 * b3;
            acc[3][0] += a3 * b0; acc[3][1] += a3 * b1; acc[3][2] += a3 * b2; acc[3][3] += a3 * b3;
        }
    }
#pragma unroll
    for (int i = 0; i < 4; ++i) {
        const size_t m = m0 + ty * 4 + i;
#pragma unroll
        for (int jj = 0; jj < 4; ++jj) {
            const int g = g0 + tx * 4 + jj;
            out[m * G4H + g] = __float2bfloat16(acc[i][jj] + bias[g]);
        }
    }
}

// ---------------------------------------------------------------------------
// K3: fused bidirectional LSTM + emission partials
// grid = 128 (64 batch x 2 dir), block = 256 (thread j = hidden unit j)
// Per step: gates = xW[b,t] + h . Wh (bf16 weights, fp32 accum); update c,h;
// emission partial em_dir[b,t,k] = sum_j h[j] * fcW[k, dir*256 + j]
// ---------------------------------------------------------------------------
__global__ void lstm_kernel(const __hip_bfloat16* __restrict__ xWf,
                            const __hip_bfloat16* __restrict__ xWb,
                            const __hip_bfloat16* __restrict__ WhFb,
                            const __hip_bfloat16* __restrict__ WhBb,
                            const float* __restrict__ fcW,
                            float* __restrict__ emf, float* __restrict__ emb_) {
    const int bi  = blockIdx.x;
    const int dir = bi & 1;
    const int b   = bi >> 1;
    const int j   = threadIdx.x;   // 0..255

    const __hip_bfloat16* xW = dir ? xWb : xWf;
    const __hip_bfloat16* Wh = dir ? WhBb : WhFb;
    float* em = dir ? emb_ : emf;

    __shared__ float h_s[HSZ];
    __shared__ float empart[8][TAGS];

    h_s[j] = 0.0f;
    float c = 0.0f;
    __syncthreads();

    // 4 gate rows for unit j: rows j, 256+j, 512+j, 768+j; each row 256 bf16 = 32 uint4
    const uint4* wr0 = (const uint4*)(Wh) + (size_t)(0 * HSZ + j) * 32;
    const uint4* wr1 = (const uint4*)(Wh) + (size_t)(1 * HSZ + j) * 32;
    const uint4* wr2 = (const uint4*)(Wh) + (size_t)(2 * HSZ + j) * 32;
    const uint4* wr3 = (const uint4*)(Wh) + (size_t)(3 * HSZ + j) * 32;

    for (int ts = 0; ts < TLEN; ++ts) {
        const int t = dir ? (TLEN - 1 - ts) : ts;
        const size_t base = ((size_t)b * TLEN + t) * G4H;
        float acc0 = __bfloat162float(xW[base + 0 * HSZ + j]);
        float acc1 = __bfloat162float(xW[base + 1 * HSZ + j]);
        float acc2 = __bfloat162float(xW[base + 2 * HSZ + j]);
        float acc3 = __bfloat162float(xW[base + 3 * HSZ + j]);

#pragma unroll 4
        for (int kc = 0; kc < 32; ++kc) {
            const float4 h0 = *(const float4*)&h_s[kc * 8];
            const float4 h1 = *(const float4*)&h_s[kc * 8 + 4];
            const uint4 wa = wr0[kc];
            const uint4 wb = wr1[kc];
            const uint4 wc = wr2[kc];
            const uint4 wd = wr3[kc];
            acc0 += bf_lo(wa.x) * h0.x + bf_hi(wa.x) * h0.y + bf_lo(wa.y) * h0.z + bf_hi(wa.y) * h0.w
                  + bf_lo(wa.z) * h1.x + bf_hi(wa.z) * h1.y + bf_lo(wa.w) * h1.z + bf_hi(wa.w) * h1.w;
            acc1 += bf_lo(wb.x) * h0.x + bf_hi(wb.x) * h0.y + bf_lo(wb.y) * h0.z + bf_hi(wb.y) * h0.w
                  + bf_lo(wb.z) * h1.x + bf_hi(wb.z) * h1.y + bf_lo(wb.w) * h1.z + bf_hi(wb.w) * h1.w;
            acc2 += bf_lo(wc.x) * h0.x + bf_hi(wc.x) * h0.y + bf_lo(wc.y) * h0.z + bf_hi(wc.y) * h0.w
                  + bf_lo(wc.z) * h1.x + bf_hi(wc.z) * h1.y + bf_lo(wc.w) * h1.z + bf_hi(wc.w) * h1.w;
            acc3 += bf_lo(wd.x) * h0.x + bf_hi(wd.x) * h0.y + bf_lo(wd.y) * h0.z + bf_hi(wd.y) * h0.w
                  + bf_lo(wd.z) * h1.x + bf_hi(wd.z) * h1.y + bf_lo(wd.w) * h1.z + bf_hi(wd.w) * h1.w;
        }

        const float ig = sigmoid_f(acc0);
        const float fg = sigmoid_f(acc1);
        const float gg = tanh_f(acc2);
        const float og = sigmoid_f(acc3);
        c = fg * c + ig * gg;
        const float hnew = og * tanh_f(c);

        __syncthreads();           // everyone done reading old h
        h_s[j] = hnew;
        __syncthreads();           // new h ready

        // emission partial: 8 parts x 32 tags
        {
            const int ke = j & 31, part = j >> 5;
            const float* fw = fcW + (size_t)ke * HID + dir * HSZ + part * 32;
            const float* hp = h_s + part * 32;
            float s = 0.0f;
#pragma unroll
            for (int i = 0; i < 32; ++i) s += hp[i] * fw[i];
            empart[part][ke] = s;
        }
        __syncthreads();           // empart ready
        if (j < TAGS) {
            float s = 0.0f;
#pragma unroll
            for (int p = 0; p < 8; ++p) s += empart[p][j];
            em[((size_t)b * TLEN + t) * TAGS + j] = s;
        }
        // next iteration's first write to empart happens only after the
        // barrier at "everyone done reading old h" -> no race with the reads above
    }
}

// ---------------------------------------------------------------------------
// K4: CRF forward algorithm + gold score per batch row
// grid = 64, block = 64 (one wave); lanes 0..31 carry alpha
// ---------------------------------------------------------------------------
__global__ void crf_kernel(const float* __restrict__ emf, const float* __restrict__ emb_,
                           const float* __restrict__ fcb,
                           const float* __restrict__ trans, const float* __restrict__ startv,
                           const float* __restrict__ endv, const int* __restrict__ y,
                           float* __restrict__ partial) {
    const int b   = blockIdx.x;
    const int tid = threadIdx.x;   // 0..63

    __shared__ float alpha_s[TAGS];
    __shared__ float trans_s[TAGS][TAGS + 1];

    for (int i = tid; i < TAGS * TAGS; i += 64)
        trans_s[i >> 5][i & 31] = trans[i];

    // em(b,t,k) = emf + emb + fcb
    const float* ef = emf  + (size_t)b * TLEN * TAGS;
    const float* eb = emb_ + (size_t)b * TLEN * TAGS;

    if (tid < TAGS)
        alpha_s[tid] = startv[tid] + ef[tid] + eb[tid] + fcb[tid];
    __syncthreads();

    for (int t = 1; t < TLEN; ++t) {
        float anew = 0.0f;
        if (tid < TAGS) {
            float mx = -3.0e38f;
#pragma unroll
            for (int k2 = 0; k2 < TAGS; ++k2) {
                float v = alpha_s[k2] + trans_s[k2][tid];
                mx = fmaxf(mx, v);
            }
            float sm = 0.0f;
#pragma unroll
            for (int k2 = 0; k2 < TAGS; ++k2) {
                float v = alpha_s[k2] + trans_s[k2][tid];
                sm += __expf(v - mx);
            }
            anew = mx + __logf(sm) + ef[t * TAGS + tid] + eb[t * TAGS + tid] + fcb[tid];
        }
        __syncthreads();
        if (tid < TAGS) alpha_s[tid] = anew;
        __syncthreads();
    }

    // logZ = logsumexp(alpha + end)
    float v = (tid < TAGS) ? (alpha_s[tid] + endv[tid]) : -1.0e30f;
    float mx = v;
#pragma unroll
    for (int off = 32; off; off >>= 1) mx = fmaxf(mx, __shfl_xor(mx, off, 64));
    float ex = __expf(v - mx);
#pragma unroll
    for (int off = 32; off; off >>= 1) ex += __shfl_xor(ex, off, 64);
    const float logZ = mx + __logf(ex);

    // gold path score
    const int* yb = y + (size_t)b * TLEN;
    float gsum = 0.0f;
    for (int t = tid; t < TLEN; t += 64) {
        const int yt = yb[t];
        gsum += ef[t * TAGS + yt] + eb[t * TAGS + yt] + fcb[yt];
    }
    for (int t = tid; t < TLEN - 1; t += 64)
        gsum += trans[yb[t] * TAGS + yb[t + 1]];
#pragma unroll
    for (int off = 32; off; off >>= 1) gsum += __shfl_xor(gsum, off, 64);

    if (tid == 0) {
        const float num = startv[yb[0]] + gsum + endv[yb[TLEN - 1]];
        partial[b] = logZ - num;
    }
}

// ---------------------------------------------------------------------------
// K5: final mean over 64 batch losses
// ---------------------------------------------------------------------------
__global__ void reduce_kernel(const float* __restrict__ partial, float* __restrict__ out) {
    float v = partial[threadIdx.x];   // 64 threads
#pragma unroll
    for (int off = 32; off; off >>= 1) v += __shfl_xor(v, off, 64);
    if (threadIdx.x == 0) out[0] = v * (1.0f / BATCH);
}

// ---------------------------------------------------------------------------
extern "C" void kernel_launch(void* const* d_in, const int* in_sizes, int n_in,
                              void* d_out, int out_size, void* d_ws, size_t ws_size,
                              hipStream_t stream) {
    (void)in_sizes; (void)n_in; (void)out_size; (void)ws_size;

    const int*   X      = (const int*)  d_in[0];
    const int*   y      = (const int*)  d_in[1];
    const float* embed  = (const float*)d_in[2];
    const float* Wi_f   = (const float*)d_in[3];
    const float* Wh_f   = (const float*)d_in[4];
    const float* b_f    = (const float*)d_in[5];
    const float* Wi_b   = (const float*)d_in[6];
    const float* Wh_b   = (const float*)d_in[7];
    const float* b_b    = (const float*)d_in[8];
    const float* fcW    = (const float*)d_in[9];
    const float* fcb    = (const float*)d_in[10];
    const float* trans  = (const float*)d_in[11];
    const float* startv = (const float*)d_in[12];
    const float* endv   = (const float*)d_in[13];
    float* out = (float*)d_out;

    // workspace layout
    char* ws = (char*)d_ws;
    __hip_bfloat16* xWf  = (__hip_bfloat16*)(ws);                          // 67108864 B
    __hip_bfloat16* xWb  = (__hip_bfloat16*)(ws + 67108864);               // 67108864 B
    __hip_bfloat16* WhFb = (__hip_bfloat16*)(ws + 134217728);              //   524288 B
    __hip_bfloat16* WhBb = (__hip_bfloat16*)(ws + 134742016);              //   524288 B
    float*          emf  = (float*)        (ws + 135266304);               //  4194304 B
    float*          emb_ = (float*)        (ws + 139460608);               //  4194304 B
    float*          prt  = (float*)        (ws + 143654912);               //      256 B

    cast_wh_kernel<<<G4H * HSZ / 256, 256, 0, stream>>>(Wh_f, Wh_b, WhFb, WhBb);

    dim3 ggrid(MTOK / 64, G4H / 64, 2);
    gemm_xw_kernel<<<ggrid, 256, 0, stream>>>(X, embed, Wi_f, b_f, Wi_b, b_b, xWf, xWb);

    lstm_kernel<<<BATCH * 2, HSZ, 0, stream>>>(xWf, xWb, WhFb, WhBb, fcW, emf, emb_);

    crf_kernel<<<BATCH, 64, 0, stream>>>(emf, emb_, fcb, trans, startv, endv, y, prt);

    reduce_kernel<<<1, 64, 0, stream>>>(prt, out);
}

// Round 2
// 8844.530 us; speedup vs baseline: 1.0026x; 1.0026x over previous
//
#include <hip/hip_runtime.h>
#include <hip/hip_fp16.h>
#include <stdint.h>

// Problem constants (NamedEntityRecognitionModel)
#define VOCAB 50000
#define TAGS  32
#define EMB   256
#define HID   512
#define HSZ   256        // per-direction hidden
#define G4H   1024       // 4*HSZ
#define BATCH 64
#define TLEN  512
#define MTOK  (BATCH * TLEN)   // 32768

// ---------------------------------------------------------------------------
// helpers
// ---------------------------------------------------------------------------
typedef _Float16 half2_t __attribute__((ext_vector_type(2)));

#if defined(__has_builtin)
#if __has_builtin(__builtin_amdgcn_fdot2)
#define HAVE_FDOT2 1
#endif
#endif

// dot of 2 f16 pairs with f32 accumulate: v_dot2_f32_f16 (1 instr = 2 MACs)
__device__ __forceinline__ float fdot2f(unsigned a, unsigned b, float c) {
    half2_t ha = __builtin_bit_cast(half2_t, a);
    half2_t hb = __builtin_bit_cast(half2_t, b);
#ifdef HAVE_FDOT2
    return __builtin_amdgcn_fdot2(ha, hb, c, false);
#else
    return c + (float)ha[0] * (float)hb[0] + (float)ha[1] * (float)hb[1];
#endif
}

__device__ __forceinline__ float sigmoid_f(float x) { return 1.0f / (1.0f + __expf(-x)); }
__device__ __forceinline__ float tanh_f(float x) {
    return 1.0f - 2.0f / (__expf(2.0f * x) + 1.0f);
}

// ---------------------------------------------------------------------------
// K1: cast Wh_f / Wh_b (each [1024,256] f32) to f16
// ---------------------------------------------------------------------------
__global__ void cast_wh_kernel(const float* __restrict__ WhF, const float* __restrict__ WhB,
                               __half* __restrict__ of, __half* __restrict__ ob) {
    int i = blockIdx.x * 256 + threadIdx.x;   // grid = 1024 blocks -> 262144
    of[i] = __float2half(WhF[i]);
    ob[i] = __float2half(WhB[i]);
}

// ---------------------------------------------------------------------------
// K2: xW[m,g] = embed[X[m]] . Wi[g] + bias[g]   (fp32 tiled GEMM, gather fused)
// grid (M/64, 1024/64, 2), block 256; f16 output
// ---------------------------------------------------------------------------
__global__ void gemm_xw_kernel(const int* __restrict__ X, const float* __restrict__ embed,
                               const float* __restrict__ WiF, const float* __restrict__ bF,
                               const float* __restrict__ WiB, const float* __restrict__ bB,
                               __half* __restrict__ xWf, __half* __restrict__ xWb) {
    __shared__ float As[64][17];
    __shared__ float Bs[64][17];
    const int tid = threadIdx.x;
    const int dir = blockIdx.z;
    const float* Wi   = dir ? WiB : WiF;
    const float* bias = dir ? bB  : bF;
    __half* out = dir ? xWb : xWf;

    const int m0 = blockIdx.x * 64;
    const int g0 = blockIdx.y * 64;
    const int tx = tid & 15, ty = tid >> 4;

    const int lrow = tid >> 2;        // 0..63 (tile row this thread loads)
    const int lk   = (tid & 3) * 4;   // 0,4,8,12
    const int erow = X[m0 + lrow];    // embedding gather index

    float acc[4][4] = {};

    for (int k0 = 0; k0 < EMB; k0 += 16) {
        const float4 av = *(const float4*)&embed[(size_t)erow * EMB + k0 + lk];
        const float4 bv = *(const float4*)&Wi[(size_t)(g0 + lrow) * EMB + k0 + lk];
        __syncthreads();
        As[lrow][lk + 0] = av.x; As[lrow][lk + 1] = av.y;
        As[lrow][lk + 2] = av.z; As[lrow][lk + 3] = av.w;
        Bs[lrow][lk + 0] = bv.x; Bs[lrow][lk + 1] = bv.y;
        Bs[lrow][lk + 2] = bv.z; Bs[lrow][lk + 3] = bv.w;
        __syncthreads();
#pragma unroll
        for (int kk = 0; kk < 16; ++kk) {
            float a0 = As[ty * 4 + 0][kk], a1 = As[ty * 4 + 1][kk];
            float a2 = As[ty * 4 + 2][kk], a3 = As[ty * 4 + 3][kk];
            float b0 = Bs[tx * 4 + 0][kk], b1 = Bs[tx * 4 + 1][kk];
            float b2 = Bs[tx * 4 + 2][kk], b3 = Bs[tx * 4 + 3][kk];
            acc[0][0] += a0 * b0; acc[0][1] += a0 * b1; acc[0][2] += a0 * b2; acc[0][3] += a0 * b3;
            acc[1][0] += a1 * b0; acc[1][1] += a1 * b1; acc[1][2] += a1 * b2; acc[1][3] += a1 * b3;
            acc[2][0] += a2 * b0; acc[2][1] += a2 * b1; acc[2][2] += a2 * b2; acc[2][3] += a2 * b3;
            acc[3][0] += a3 * b0; acc[3][1] += a3 * b1; acc[3][2] += a3 * b2; acc[3][3] += a3 * b3;
        }
    }
#pragma unroll
    for (int i = 0; i < 4; ++i) {
        const size_t m = m0 + ty * 4 + i;
#pragma unroll
        for (int jj = 0; jj < 4; ++jj) {
            const int g = g0 + tx * 4 + jj;
            out[m * G4H + g] = __float2half(acc[i][jj] + bias[g]);
        }
    }
}

// ---------------------------------------------------------------------------
// K3: fused bidirectional LSTM + emission partials (f16 dot2 version)
// grid = (32, 2): batch-PAIR p, direction. block = 1024 threads (16 waves).
// Thread g owns gate row g (of 1024); computes it for BOTH batches of the
// pair (halves Wh L2 traffic). h, gates, fcW-slice live in LDS.
// ---------------------------------------------------------------------------
__global__ __launch_bounds__(1024, 4)
void lstm_kernel(const __half* __restrict__ xWf, const __half* __restrict__ xWb,
                 const __half* __restrict__ WhF, const __half* __restrict__ WhB,
                 const float* __restrict__ fcW,
                 float* __restrict__ emf, float* __restrict__ emb_) {
    const int pair = blockIdx.x;      // 0..31
    const int dir  = blockIdx.y;      // 0..1
    const int b0   = pair * 2;
    const int tid  = threadIdx.x;     // 0..1023

    const __half* xW = dir ? xWb : xWf;
    const __half* Wh = dir ? WhB : WhF;
    float* em = dir ? emb_ : emf;

    __shared__ ushort hbuf[2][256];          // h as f16, per batch of pair
    __shared__ float  gbuf[2][G4H];          // gate preactivations
    __shared__ float  fcs[256][32];          // fcW slice transposed: fcs[j][k]
    __shared__ float  empart[2][16][33];     // padded: bank = (part+k)%32

    // preload fcW slice for this direction (one-time)
    for (int i = tid; i < 256 * 32; i += 1024) {
        const int j = i >> 5, k = i & 31;
        fcs[j][k] = fcW[(size_t)k * HID + dir * HSZ + j];
    }
    if (tid < 512) ((ushort*)hbuf)[tid] = 0;   // h0 = 0 (f16 zero)
    float c = 0.0f;                             // cell state for tid<512
    __syncthreads();

    const uint4* wrow = (const uint4*)Wh + (size_t)tid * 32;  // row = 256 f16 = 32 uint4
    const uint4* hb0  = (const uint4*)&hbuf[0][0];            // 32 uint4
    const uint4* hb1  = (const uint4*)&hbuf[1][0];

    for (int ts = 0; ts < TLEN; ++ts) {
        const int t = dir ? (TLEN - 1 - ts) : ts;

        // ---- phase 1: gate matvec (all 1024 threads, 1 row x 2 batches) ----
        float a0 = (float)xW[((size_t)b0 * TLEN + t) * G4H + tid];
        float a1 = (float)xW[((size_t)(b0 + 1) * TLEN + t) * G4H + tid];
#pragma unroll 4
        for (int kc = 0; kc < 32; ++kc) {
            const uint4 w  = wrow[kc];   // 8 f16 weights (L2-resident)
            const uint4 h0 = hb0[kc];    // LDS broadcast (all lanes same addr)
            const uint4 h1 = hb1[kc];
            a0 = fdot2f(w.x, h0.x, a0); a0 = fdot2f(w.y, h0.y, a0);
            a0 = fdot2f(w.z, h0.z, a0); a0 = fdot2f(w.w, h0.w, a0);
            a1 = fdot2f(w.x, h1.x, a1); a1 = fdot2f(w.y, h1.y, a1);
            a1 = fdot2f(w.z, h1.z, a1); a1 = fdot2f(w.w, h1.w, a1);
        }
        gbuf[0][tid] = a0;
        gbuf[1][tid] = a1;
        __syncthreads();                           // B1: gates ready

        // ---- phase 2: cell update (512 threads: batch bb, unit j) ----
        if (tid < 512) {
            const int bb = tid >> 8, j = tid & 255;
            const float ig = sigmoid_f(gbuf[bb][          j]);
            const float fg = sigmoid_f(gbuf[bb][HSZ     + j]);
            const float gg = tanh_f   (gbuf[bb][2 * HSZ + j]);
            const float og = sigmoid_f(gbuf[bb][3 * HSZ + j]);
            c = fg * c + ig * gg;
            const float h = og * tanh_f(c);
            hbuf[bb][j] = __half_as_ushort(__float2half(h));
        }
        __syncthreads();                           // B2: h ready

        // ---- phase 3a: emission partials (all threads) ----
        {
            const int bb = tid >> 9, r = tid & 511;
            const int k = r & 31, part = r >> 5;   // 16 parts x 32 tags
            float s = 0.0f;
#pragma unroll
            for (int i = 0; i < 16; ++i) {
                const int j = part * 16 + i;
                s += (float)__ushort_as_half(hbuf[bb][j]) * fcs[j][k];
            }
            empart[bb][part][k] = s;
        }
        __syncthreads();                           // B3: empart ready

        // ---- phase 3b: reduce + store emission ----
        if (tid < 64) {
            const int bb = tid >> 5, k = tid & 31;
            float s = 0.0f;
#pragma unroll
            for (int p = 0; p < 16; ++p) s += empart[bb][p][k];
            em[((size_t)(b0 + bb) * TLEN + t) * TAGS + k] = s;
        }
        // no barrier needed: B1 of next iter orders empart/hbuf/gbuf reuse
    }
}

// ---------------------------------------------------------------------------
// K4: CRF forward algorithm + gold score per batch row
// grid = 64, block = 64 (one wave)
// ---------------------------------------------------------------------------
__global__ void crf_kernel(const float* __restrict__ emf, const float* __restrict__ emb_,
                           const float* __restrict__ fcb,
                           const float* __restrict__ trans, const float* __restrict__ startv,
                           const float* __restrict__ endv, const int* __restrict__ y,
                           float* __restrict__ partial) {
    const int b   = blockIdx.x;
    const int tid = threadIdx.x;   // 0..63

    __shared__ float alpha_s[TAGS];
    __shared__ float trans_s[TAGS][TAGS + 1];

    for (int i = tid; i < TAGS * TAGS; i += 64)
        trans_s[i >> 5][i & 31] = trans[i];

    const float* ef = emf  + (size_t)b * TLEN * TAGS;
    const float* eb = emb_ + (size_t)b * TLEN * TAGS;

    if (tid < TAGS)
        alpha_s[tid] = startv[tid] + ef[tid] + eb[tid] + fcb[tid];
    __syncthreads();

    for (int t = 1; t < TLEN; ++t) {
        float anew = 0.0f;
        if (tid < TAGS) {
            float mx = -3.0e38f;
#pragma unroll
            for (int k2 = 0; k2 < TAGS; ++k2) {
                float v = alpha_s[k2] + trans_s[k2][tid];
                mx = fmaxf(mx, v);
            }
            float sm = 0.0f;
#pragma unroll
            for (int k2 = 0; k2 < TAGS; ++k2) {
                float v = alpha_s[k2] + trans_s[k2][tid];
                sm += __expf(v - mx);
            }
            anew = mx + __logf(sm) + ef[t * TAGS + tid] + eb[t * TAGS + tid] + fcb[tid];
        }
        __syncthreads();
        if (tid < TAGS) alpha_s[tid] = anew;
        __syncthreads();
    }

    float v = (tid < TAGS) ? (alpha_s[tid] + endv[tid]) : -1.0e30f;
    float mx = v;
#pragma unroll
    for (int off = 32; off; off >>= 1) mx = fmaxf(mx, __shfl_xor(mx, off, 64));
    float ex = __expf(v - mx);
#pragma unroll
    for (int off = 32; off; off >>= 1) ex += __shfl_xor(ex, off, 64);
    const float logZ = mx + __logf(ex);

    const int* yb = y + (size_t)b * TLEN;
    float gsum = 0.0f;
    for (int t = tid; t < TLEN; t += 64) {
        const int yt = yb[t];
        gsum += ef[t * TAGS + yt] + eb[t * TAGS + yt] + fcb[yt];
    }
    for (int t = tid; t < TLEN - 1; t += 64)
        gsum += trans[yb[t] * TAGS + yb[t + 1]];
#pragma unroll
    for (int off = 32; off; off >>= 1) gsum += __shfl_xor(gsum, off, 64);

    if (tid == 0) {
        const float num = startv[yb[0]] + gsum + endv[yb[TLEN - 1]];
        partial[b] = logZ - num;
    }
}

// ---------------------------------------------------------------------------
// K5: final mean over 64 batch losses
// ---------------------------------------------------------------------------
__global__ void reduce_kernel(const float* __restrict__ partial, float* __restrict__ out) {
    float v = partial[threadIdx.x];   // 64 threads
#pragma unroll
    for (int off = 32; off; off >>= 1) v += __shfl_xor(v, off, 64);
    if (threadIdx.x == 0) out[0] = v * (1.0f / BATCH);
}

// ---------------------------------------------------------------------------
extern "C" void kernel_launch(void* const* d_in, const int* in_sizes, int n_in,
                              void* d_out, int out_size, void* d_ws, size_t ws_size,
                              hipStream_t stream) {
    (void)in_sizes; (void)n_in; (void)out_size; (void)ws_size;

    const int*   X      = (const int*)  d_in[0];
    const int*   y      = (const int*)  d_in[1];
    const float* embed  = (const float*)d_in[2];
    const float* Wi_f   = (const float*)d_in[3];
    const float* Wh_f   = (const float*)d_in[4];
    const float* b_f    = (const float*)d_in[5];
    const float* Wi_b   = (const float*)d_in[6];
    const float* Wh_b   = (const float*)d_in[7];
    const float* b_b    = (const float*)d_in[8];
    const float* fcW    = (const float*)d_in[9];
    const float* fcb    = (const float*)d_in[10];
    const float* trans  = (const float*)d_in[11];
    const float* startv = (const float*)d_in[12];
    const float* endv   = (const float*)d_in[13];
    float* out = (float*)d_out;

    // workspace layout
    char* ws = (char*)d_ws;
    __half* xWf  = (__half*)(ws);                          // 67108864 B
    __half* xWb  = (__half*)(ws + 67108864);               // 67108864 B
    __half* WhFh = (__half*)(ws + 134217728);              //   524288 B
    __half* WhBh = (__half*)(ws + 134742016);              //   524288 B
    float*  emf  = (float*) (ws + 135266304);              //  4194304 B
    float*  emb_ = (float*) (ws + 139460608);              //  4194304 B
    float*  prt  = (float*) (ws + 143654912);              //      256 B

    cast_wh_kernel<<<G4H * HSZ / 256, 256, 0, stream>>>(Wh_f, Wh_b, WhFh, WhBh);

    dim3 ggrid(MTOK / 64, G4H / 64, 2);
    gemm_xw_kernel<<<ggrid, 256, 0, stream>>>(X, embed, Wi_f, b_f, Wi_b, b_b, xWf, xWb);

    dim3 lgrid(BATCH / 2, 2);
    lstm_kernel<<<lgrid, 1024, 0, stream>>>(xWf, xWb, WhFh, WhBh, fcW, emf, emb_);

    crf_kernel<<<BATCH, 64, 0, stream>>>(emf, emb_, fcb, trans, startv, endv, y, prt);

    reduce_kernel<<<1, 64, 0, stream>>>(prt, out);
}

// Round 3
// 6584.178 us; speedup vs baseline: 1.3468x; 1.3433x over previous
//
#include <hip/hip_runtime.h>
#include <hip/hip_fp16.h>
#include <stdint.h>

// Problem constants (NamedEntityRecognitionModel)
#define TAGS  32
#define EMB   256
#define HID   512
#define HSZ   256        // per-direction hidden
#define G4H   1024       // 4*HSZ
#define BATCH 64
#define TLEN  512

typedef _Float16 half8  __attribute__((ext_vector_type(8)));
typedef _Float16 half2v __attribute__((ext_vector_type(2)));
typedef float    f32x4  __attribute__((ext_vector_type(4)));

#if defined(__has_builtin)
#if __has_builtin(__builtin_amdgcn_fdot2)
#define HAVE_FDOT2 1
#endif
#endif

__device__ __forceinline__ float fdot2f(unsigned a, unsigned b, float c) {
    half2v ha = __builtin_bit_cast(half2v, a);
    half2v hb = __builtin_bit_cast(half2v, b);
#ifdef HAVE_FDOT2
    return __builtin_amdgcn_fdot2(ha, hb, c, false);
#else
    return c + (float)ha[0]*(float)hb[0] + (float)ha[1]*(float)hb[1];
#endif
}
__device__ __forceinline__ float sigmoid_f(float x){ return 1.0f/(1.0f+__expf(-x)); }
__device__ __forceinline__ float tanh_f(float x){ return 1.0f - 2.0f/(__expf(2.0f*x)+1.0f); }

// ---------------------------------------------------------------------------
// K1: xWT[dir][t][n][b] = embed[X[b][t]] . Wi[n] + bias[n]  (f16 out, transposed)
// grid (512 t, 16 ntiles, 2 dir), block 256. fp32 LDS-tiled GEMM + LDS transpose.
// ---------------------------------------------------------------------------
__global__ __launch_bounds__(256)
void gemm_xwt_kernel(const int* __restrict__ X, const float* __restrict__ embed,
                     const float* __restrict__ WiF, const float* __restrict__ bF,
                     const float* __restrict__ WiB, const float* __restrict__ bB,
                     __half* __restrict__ xWT) {
    __shared__ float As[64][17];
    __shared__ float Bs[64][17];
    __shared__ ushort tr[64][72];         // [n_local][b], 144B row stride (16B aligned)

    const int tid = threadIdx.x;
    const int t   = blockIdx.x;           // 0..511
    const int n0  = blockIdx.y * 64;      // 0..960
    const int dir = blockIdx.z;
    const float* Wi   = dir ? WiB : WiF;
    const float* bias = dir ? bB  : bF;

    const int tx = tid & 15, ty = tid >> 4;
    const int lrow = tid >> 2;            // 0..63: batch (A) / n-row (B)
    const int lk   = (tid & 3) * 4;
    const int erow = X[lrow * TLEN + t];  // gather: batch lrow, token t

    float acc[4][4] = {};
    for (int k0 = 0; k0 < EMB; k0 += 16) {
        const float4 av = *(const float4*)&embed[(size_t)erow * EMB + k0 + lk];
        const float4 bv = *(const float4*)&Wi[(size_t)(n0 + lrow) * EMB + k0 + lk];
        __syncthreads();
        As[lrow][lk+0]=av.x; As[lrow][lk+1]=av.y; As[lrow][lk+2]=av.z; As[lrow][lk+3]=av.w;
        Bs[lrow][lk+0]=bv.x; Bs[lrow][lk+1]=bv.y; Bs[lrow][lk+2]=bv.z; Bs[lrow][lk+3]=bv.w;
        __syncthreads();
#pragma unroll
        for (int kk = 0; kk < 16; ++kk) {
            float a0=As[ty*4+0][kk], a1=As[ty*4+1][kk], a2=As[ty*4+2][kk], a3=As[ty*4+3][kk];
            float b0=Bs[tx*4+0][kk], b1=Bs[tx*4+1][kk], b2=Bs[tx*4+2][kk], b3=Bs[tx*4+3][kk];
            acc[0][0]+=a0*b0; acc[0][1]+=a0*b1; acc[0][2]+=a0*b2; acc[0][3]+=a0*b3;
            acc[1][0]+=a1*b0; acc[1][1]+=a1*b1; acc[1][2]+=a1*b2; acc[1][3]+=a1*b3;
            acc[2][0]+=a2*b0; acc[2][1]+=a2*b1; acc[2][2]+=a2*b2; acc[2][3]+=a2*b3;
            acc[3][0]+=a3*b0; acc[3][1]+=a3*b1; acc[3][2]+=a3*b2; acc[3][3]+=a3*b3;
        }
    }
    __syncthreads();
#pragma unroll
    for (int i = 0; i < 4; ++i)
#pragma unroll
        for (int jj = 0; jj < 4; ++jj) {
            const int n = tx*4 + jj, b = ty*4 + i;
            tr[n][b] = __half_as_ushort(__float2half(acc[i][jj] + bias[n0 + n]));
        }
    __syncthreads();
    __half* dst = xWT + (((size_t)dir * TLEN + t) * G4H + n0) * BATCH;
#pragma unroll
    for (int q = 0; q < 2; ++q) {
        const int sid = tid + q*256;
        const int row = sid >> 3, seg = sid & 7;
        const uint4 v = *(const uint4*)&tr[row][seg*8];
        *(uint4*)(dst + (size_t)row * BATCH + seg*8) = v;
    }
}

// ---------------------------------------------------------------------------
// K2: persistent bidirectional LSTM, Wh LDS-resident, MFMA recurrence.
// grid = 8 blocks: (slice s in 0..3, dir in 0..1); block = 256 (4 waves).
// Block owns units [64s, 64s+64) for all 64 batches. Per step:
//   gates[64b, 256col] = hist[t_prev] x Wh_slice (MFMA) + xWT(t) (acc init)
// h exchanged via global hist + 4-block flag barrier.
// ---------------------------------------------------------------------------
__global__ __launch_bounds__(256, 1)
void lstm_kernel(const __half* __restrict__ xWT,
                 const float* __restrict__ WhF, const float* __restrict__ WhB,
                 __half* __restrict__ hist, int* __restrict__ flags) {
    const int s   = blockIdx.x & 3;
    const int dir = blockIdx.x >> 2;
    const int tid = threadIdx.x;
    const int lane = tid & 63;
    const int w    = tid >> 6;        // wave 0..3: units [64s+16w, +16)
    const int l15  = lane & 15;
    const int lp   = lane >> 4;       // 0..3

    __shared__ ushort whl[256 * 256]; // 128 KB: [n_local 256][k 256] f16, XOR-swizzled

    const float* Wh = dir ? WhB : WhF;

    // ---- stage Wh slice: n_local = g*64+u  <-  global row g*256 + s*64 + u ----
    {
        const int nl = tid;                  // one row per thread
        const int g = nl >> 6, u = nl & 63;
        const float* src = Wh + (size_t)(g * 256 + s * 64 + u) * HSZ;
        char* base = (char*)whl;
        const int swz = (nl & 7) << 4;
#pragma unroll
        for (int k0 = 0; k0 < 256; k0 += 8) {
            const float4 x0 = *(const float4*)(src + k0);
            const float4 x1 = *(const float4*)(src + k0 + 4);
            half8 h;
            h[0]=(_Float16)x0.x; h[1]=(_Float16)x0.y; h[2]=(_Float16)x0.z; h[3]=(_Float16)x0.w;
            h[4]=(_Float16)x1.x; h[5]=(_Float16)x1.y; h[6]=(_Float16)x1.z; h[7]=(_Float16)x1.w;
            *(half8*)(base + nl * 512 + ((k0 * 2) ^ swz)) = h;
        }
    }
    __syncthreads();

    __half* histD = hist + (size_t)dir * TLEN * BATCH * HSZ;
    const int ubase = s * 64 + w * 16 + l15;   // unit index j of this lane

    int rowb[4], rswz[4];
#pragma unroll
    for (int g = 0; g < 4; ++g) {
        const int nl = g * 64 + w * 16 + l15;
        rowb[g] = nl * 512;
        rswz[g] = (nl & 7) << 4;
    }

    f32x4 acc[4][4];       // [gate g][m-tile]
    float c[16];           // cell state: [m*4+r]
#pragma unroll
    for (int i = 0; i < 16; ++i) c[i] = 0.0f;
    uint2 xwp[4][4];       // prefetched xWT for current t: [g][m] = 4 f16 (b0..b0+3)

    const __half* xwD = xWT + (size_t)dir * TLEN * G4H * BATCH;
#define PREFETCH_XW(T)                                                          \
    {                                                                           \
        const __half* p = xwD + (size_t)(T) * G4H * BATCH;                      \
        _Pragma("unroll")                                                       \
        for (int g = 0; g < 4; ++g) {                                           \
            const __half* pg = p + (size_t)(g * 256 + ubase) * BATCH + lp * 4;  \
            _Pragma("unroll")                                                   \
            for (int m = 0; m < 4; ++m)                                         \
                xwp[g][m] = *(const uint2*)(pg + m * 16);                       \
        }                                                                       \
    }

    PREFETCH_XW(dir ? (TLEN - 1) : 0);

    for (int ts = 0; ts < TLEN; ++ts) {
        const int t     = dir ? (TLEN - 1 - ts) : ts;
        const int tprev = dir ? (t + 1) : (t - 1);

        // acc <- xW(t)
#pragma unroll
        for (int g = 0; g < 4; ++g)
#pragma unroll
            for (int m = 0; m < 4; ++m) {
                const half2v lo = __builtin_bit_cast(half2v, xwp[g][m].x);
                const half2v hi = __builtin_bit_cast(half2v, xwp[g][m].y);
                f32x4 a; a[0]=(float)lo[0]; a[1]=(float)lo[1]; a[2]=(float)hi[0]; a[3]=(float)hi[1];
                acc[g][m] = a;
            }

        if (ts > 0) {
            // wait for generation ts (h(t_prev) complete from all 4 slices)
            if (tid == 0) {
#pragma unroll
                for (int o = 0; o < 4; ++o) {
                    if (o == s) continue;
                    while (__hip_atomic_load(&flags[dir*4 + o], __ATOMIC_RELAXED,
                                             __HIP_MEMORY_SCOPE_AGENT) < ts) { }
                }
            }
            __syncthreads();
            __threadfence();   // acquire: invalidate caches before reading remote h

            const __half* hp = histD + (size_t)tprev * (BATCH * HSZ);
            half8 af[4];
#pragma unroll
            for (int m = 0; m < 4; ++m)
                af[m] = *(const half8*)(hp + (m * 16 + l15) * HSZ + lp * 8);
#pragma unroll
            for (int k0 = 0; k0 < 8; ++k0) {
                half8 an[4];
                if (k0 < 7) {
#pragma unroll
                    for (int m = 0; m < 4; ++m)
                        an[m] = *(const half8*)(hp + (m*16 + l15) * HSZ + lp*8 + 32*(k0+1));
                }
#pragma unroll
                for (int g = 0; g < 4; ++g) {
                    const half8 bf = *(const half8*)((const char*)whl + rowb[g]
                                        + ((k0 * 64 + lp * 16) ^ rswz[g]));
#pragma unroll
                    for (int m = 0; m < 4; ++m)
                        acc[g][m] = __builtin_amdgcn_mfma_f32_16x16x32_f16(af[m], bf, acc[g][m], 0, 0, 0);
                }
                if (k0 < 7) {
#pragma unroll
                    for (int m = 0; m < 4; ++m) af[m] = an[m];
                }
            }
        }

        // cell update + h store
        __half* hout = histD + (size_t)t * (BATCH * HSZ);
#pragma unroll
        for (int m = 0; m < 4; ++m)
#pragma unroll
            for (int r = 0; r < 4; ++r) {
                const float ig = sigmoid_f(acc[0][m][r]);
                const float fg = sigmoid_f(acc[1][m][r]);
                const float gg = tanh_f   (acc[2][m][r]);
                const float og = sigmoid_f(acc[3][m][r]);
                float cc = c[m*4 + r];
                cc = fg * cc + ig * gg;
                c[m*4 + r] = cc;
                const float hv = og * tanh_f(cc);
                const int b = m * 16 + lp * 4 + r;
                hout[(size_t)b * HSZ + ubase] = __float2half(hv);
            }

        if (ts + 1 < TLEN) PREFETCH_XW(dir ? (t - 1) : (t + 1));

        __threadfence();       // release: drain h stores agent-wide
        __syncthreads();
        if (tid == 0)
            __hip_atomic_store(&flags[dir*4 + s], ts + 1, __ATOMIC_RELAXED,
                               __HIP_MEMORY_SCOPE_AGENT);
    }
#undef PREFETCH_XW
}

// ---------------------------------------------------------------------------
// K3: emissions em[b][t][k] = hf(t,b,:).fcW[k,0:256] + hb(t,b,:).fcW[k,256:512]
// grid = 64b x 8 tchunks = 512 blocks, block 256.
// ---------------------------------------------------------------------------
__global__ __launch_bounds__(256)
void em_kernel(const __half* __restrict__ hist, const float* __restrict__ fcW,
               float* __restrict__ em) {
    const int b   = blockIdx.x >> 3;
    const int t0  = (blockIdx.x & 7) * 64;
    const int tid = threadIdx.x;

    __shared__ ushort hf[64][264];
    __shared__ ushort hb[64][264];
    __shared__ ushort fcs[32][520];

    for (int i = tid; i < 32 * 512; i += 256) {
        const int k = i >> 9, j = i & 511;
        fcs[k][j] = __half_as_ushort(__float2half(fcW[(size_t)k * HID + j]));
    }
    const __half* hfp = hist;
    const __half* hbp = hist + (size_t)TLEN * BATCH * HSZ;
    for (int i = tid; i < 64 * 32; i += 256) {
        const int row = i >> 5, seg = i & 31;
        const uint4 vf = *(const uint4*)(hfp + ((size_t)(t0+row) * BATCH + b) * HSZ + seg*8);
        const uint4 vb = *(const uint4*)(hbp + ((size_t)(t0+row) * BATCH + b) * HSZ + seg*8);
        *(uint4*)&hf[row][seg*8] = vf;
        *(uint4*)&hb[row][seg*8] = vb;
    }
    __syncthreads();

    const int tok = tid >> 2;     // 0..63
    const int kq  = tid & 3;      // k = kq*8 + kk
    float s[8] = {0,0,0,0,0,0,0,0};
    for (int j2 = 0; j2 < 128; ++j2) {
        const unsigned hfv = *(const unsigned*)&hf[tok][j2*2];
        const unsigned hbv = *(const unsigned*)&hb[tok][j2*2];
#pragma unroll
        for (int kk = 0; kk < 8; ++kk) {
            const int k = kq*8 + kk;
            s[kk] = fdot2f(hfv, *(const unsigned*)&fcs[k][j2*2], s[kk]);
            s[kk] = fdot2f(hbv, *(const unsigned*)&fcs[k][256 + j2*2], s[kk]);
        }
    }
    float* dst = em + ((size_t)b * TLEN + t0 + tok) * TAGS + kq*8;
#pragma unroll
    for (int kk = 0; kk < 8; ++kk) dst[kk] = s[kk];
}

// ---------------------------------------------------------------------------
// K4: CRF forward + gold score per batch row. grid 64, block 64.
// ---------------------------------------------------------------------------
__global__ void crf_kernel(const float* __restrict__ em, const float* __restrict__ fcb,
                           const float* __restrict__ trans, const float* __restrict__ startv,
                           const float* __restrict__ endv, const int* __restrict__ y,
                           float* __restrict__ partial) {
    const int b   = blockIdx.x;
    const int tid = threadIdx.x;

    __shared__ float alpha_s[TAGS];
    __shared__ float trans_s[TAGS][TAGS + 1];

    for (int i = tid; i < TAGS * TAGS; i += 64)
        trans_s[i >> 5][i & 31] = trans[i];

    const float* e = em + (size_t)b * TLEN * TAGS;

    if (tid < TAGS)
        alpha_s[tid] = startv[tid] + e[tid] + fcb[tid];
    __syncthreads();

    for (int t = 1; t < TLEN; ++t) {
        float anew = 0.0f;
        if (tid < TAGS) {
            float mx = -3.0e38f;
#pragma unroll
            for (int k2 = 0; k2 < TAGS; ++k2)
                mx = fmaxf(mx, alpha_s[k2] + trans_s[k2][tid]);
            float sm = 0.0f;
#pragma unroll
            for (int k2 = 0; k2 < TAGS; ++k2)
                sm += __expf(alpha_s[k2] + trans_s[k2][tid] - mx);
            anew = mx + __logf(sm) + e[t * TAGS + tid] + fcb[tid];
        }
        __syncthreads();
        if (tid < TAGS) alpha_s[tid] = anew;
        __syncthreads();
    }

    float v = (tid < TAGS) ? (alpha_s[tid] + endv[tid]) : -1.0e30f;
    float mx = v;
#pragma unroll
    for (int off = 32; off; off >>= 1) mx = fmaxf(mx, __shfl_xor(mx, off, 64));
    float ex = __expf(v - mx);
#pragma unroll
    for (int off = 32; off; off >>= 1) ex += __shfl_xor(ex, off, 64);
    const float logZ = mx + __logf(ex);

    const int* yb = y + (size_t)b * TLEN;
    float gsum = 0.0f;
    for (int t = tid; t < TLEN; t += 64) {
        const int yt = yb[t];
        gsum += e[t * TAGS + yt] + fcb[yt];
    }
    for (int t = tid; t < TLEN - 1; t += 64)
        gsum += trans[yb[t] * TAGS + yb[t + 1]];
#pragma unroll
    for (int off = 32; off; off >>= 1) gsum += __shfl_xor(gsum, off, 64);

    if (tid == 0) {
        const float num = startv[yb[0]] + gsum + endv[yb[TLEN - 1]];
        partial[b] = logZ - num;
    }
}

// ---------------------------------------------------------------------------
// K5: final mean
// ---------------------------------------------------------------------------
__global__ void reduce_kernel(const float* __restrict__ partial, float* __restrict__ out) {
    float v = partial[threadIdx.x];
#pragma unroll
    for (int off = 32; off; off >>= 1) v += __shfl_xor(v, off, 64);
    if (threadIdx.x == 0) out[0] = v * (1.0f / BATCH);
}

// ---------------------------------------------------------------------------
extern "C" void kernel_launch(void* const* d_in, const int* in_sizes, int n_in,
                              void* d_out, int out_size, void* d_ws, size_t ws_size,
                              hipStream_t stream) {
    (void)in_sizes; (void)n_in; (void)out_size; (void)ws_size;

    const int*   X      = (const int*)  d_in[0];
    const int*   y      = (const int*)  d_in[1];
    const float* embed  = (const float*)d_in[2];
    const float* Wi_f   = (const float*)d_in[3];
    const float* Wh_f   = (const float*)d_in[4];
    const float* b_f    = (const float*)d_in[5];
    const float* Wi_b   = (const float*)d_in[6];
    const float* Wh_b   = (const float*)d_in[7];
    const float* b_b    = (const float*)d_in[8];
    const float* fcW    = (const float*)d_in[9];
    const float* fcb    = (const float*)d_in[10];
    const float* trans  = (const float*)d_in[11];
    const float* startv = (const float*)d_in[12];
    const float* endv   = (const float*)d_in[13];
    float* out = (float*)d_out;

    // workspace layout
    char* ws = (char*)d_ws;
    __half* xWT  = (__half*)(ws);                    // [2][512][1024][64] f16 = 134217728 B
    __half* hist = (__half*)(ws + 134217728);        // [2][512][64][256] f16 =  33554432 B
    float*  em   = (float*) (ws + 167772160);        // [64][512][32] f32     =   4194304 B
    float*  prt  = (float*) (ws + 171966464);        //                            256 B
    int*    flg  = (int*)   (ws + 171966720);        // [2][4] generation flags     64 B

    hipMemsetAsync(flg, 0, 64, stream);

    dim3 ggrid(TLEN, G4H / 64, 2);
    gemm_xwt_kernel<<<ggrid, 256, 0, stream>>>(X, embed, Wi_f, b_f, Wi_b, b_b, xWT);

    lstm_kernel<<<8, 256, 0, stream>>>(xWT, Wh_f, Wh_b, hist, flg);

    em_kernel<<<BATCH * 8, 256, 0, stream>>>(hist, fcW, em);

    crf_kernel<<<BATCH, 64, 0, stream>>>(em, fcb, trans, startv, endv, y, prt);

    reduce_kernel<<<1, 64, 0, stream>>>(prt, out);
}